// Round 2
// baseline (155.886 us; speedup 1.0000x reference)
//
#include <hip/hip_runtime.h>
#include <hip/hip_bf16.h>

// NormPool2d: 3x3 reflect-padded window, output = mean - unbiased std.
// x: (16, 96, 224, 224) fp32 -> out same shape, fp32.
//
// Round 2: float4-vectorized streaming. Each thread owns a 4-wide w-strip
// over a 56-row chunk (H split into 4 chunks to keep TLP: grid stays
// 1344x256 = ~21 waves/CU). Per row: 1 float4 load + 2 scalar neighbor
// loads (L1-absorbed overlap) + 1 float4 store. Vertical 3-row ring of
// (rowsum, rowsumsq) float4s; reflect edges handled by re-reading the
// mirror row (h=0 window = row0 + 2*row1 emerges naturally).

#define NP_W 224
#define NP_H 224
#define NP_PLANES (16 * 96)
#define NP_STRIPS (NP_W / 4)   // 56
#define NP_CHUNKS 4
#define NP_CROWS (NP_H / NP_CHUNKS)  // 56

__global__ __launch_bounds__(256) void NormPool2d_kernel(
    const float* __restrict__ x, float* __restrict__ out) {
    const int W = NP_W, H = NP_H;
    int f = blockIdx.x * blockDim.x + threadIdx.x;
    // total threads = PLANES * CHUNKS * STRIPS = 344064 = 1344*256 exactly
    int strip = f % NP_STRIPS;
    int t = f / NP_STRIPS;
    int chunk = t % NP_CHUNKS;
    int plane = t / NP_CHUNKS;
    int w = strip * 4;

    const float* __restrict__ xp = x + (size_t)plane * (H * W);
    float* __restrict__ op = out + (size_t)plane * (H * W) + w;

    const bool left_edge = (w == 0);
    const bool right_edge = (w == W - 4);

    // row sums (s) and sum-of-squares (q) for 4 outputs at physical row h
    auto rowv = [&](int h, float4& rs, float4& rq) {
        const float* r = xp + (size_t)h * W;
        float4 v = *reinterpret_cast<const float4*>(r + w);
        float lf = left_edge ? v.y : r[w - 1];     // reflect: x[-1] -> x[1]
        float rt = right_edge ? v.z : r[w + 4];    // reflect: x[224] -> x[222]
        rs.x = lf + v.x + v.y;
        rs.y = v.x + v.y + v.z;
        rs.z = v.y + v.z + v.w;
        rs.w = v.z + v.w + rt;
        float l2 = lf * lf, a2 = v.x * v.x, b2 = v.y * v.y;
        float c2 = v.z * v.z, d2 = v.w * v.w, r2 = rt * rt;
        rq.x = l2 + a2 + b2;
        rq.y = a2 + b2 + c2;
        rq.z = b2 + c2 + d2;
        rq.w = c2 + d2 + r2;
    };

    auto finish = [&](float s, float q) -> float {
        float mean = s * (1.f / 9.f);
        float var = (q - s * mean) * 0.125f;  // unbiased: (ss - s^2/9)/8
        return mean - sqrtf(fmaxf(var, 0.f));
    };

    int r0 = chunk * NP_CROWS;
    int r1 = r0 + NP_CROWS;

    float4 ps, pq, cs, cq;
    int hm = (r0 == 0) ? 1 : r0 - 1;  // reflect: row -1 -> row 1
    rowv(hm, ps, pq);
    rowv(r0, cs, cq);

    for (int h = r0; h < r1; ++h) {
        int hp = (h == H - 1) ? H - 2 : h + 1;  // reflect: row 224 -> 222
        float4 ns, nq;
        rowv(hp, ns, nq);

        float4 o;
        o.x = finish(ps.x + cs.x + ns.x, pq.x + cq.x + nq.x);
        o.y = finish(ps.y + cs.y + ns.y, pq.y + cq.y + nq.y);
        o.z = finish(ps.z + cs.z + ns.z, pq.z + cq.z + nq.z);
        o.w = finish(ps.w + cs.w + ns.w, pq.w + cq.w + nq.w);
        *reinterpret_cast<float4*>(op + (size_t)h * W) = o;

        ps = cs; pq = cq;
        cs = ns; cq = nq;
    }
}

extern "C" void kernel_launch(void* const* d_in, const int* in_sizes, int n_in,
                              void* d_out, int out_size, void* d_ws, size_t ws_size,
                              hipStream_t stream) {
    const float* x = (const float*)d_in[0];
    float* out = (float*)d_out;
    (void)in_sizes; (void)n_in; (void)out_size; (void)d_ws; (void)ws_size;

    const int total_threads = NP_PLANES * NP_CHUNKS * NP_STRIPS;  // 344064
    const int block = 256;
    const int grid = total_threads / block;  // 1344
    NormPool2d_kernel<<<grid, block, 0, stream>>>(x, out);
}

// Round 3
// 147.661 us; speedup vs baseline: 1.0557x; 1.0557x over previous
//
#include <hip/hip_runtime.h>
#include <hip/hip_bf16.h>

// NormPool2d: 3x3 reflect-padded window, output = mean - unbiased std.
// x: (16, 96, 224, 224) fp32 -> out same shape, fp32.
//
// Round 3: attack the latency/MLP regime found in round 2 (2.7 TB/s, VALU 40%,
// occupancy 53%, VGPR=24 -> no load pipelining). Changes:
//  - Explicit depth-2 software pipeline: row h+2's raw loads are issued a full
//    iteration before their sums are consumed; #pragma unroll 3 lets up to
//    ~3 iterations of loads be in flight per wave.
//  - CHUNKS 4 -> 8 (28 rows/thread): grid 1344 -> 2688 blocks (10.5/CU),
//    halves the integer-imbalance tail and doubles TLP.
// Cost: chunk-boundary re-reads 30/28 = +7% read traffic. HBM ideal ~640 MB.

#define NP_W 224
#define NP_H 224
#define NP_PLANES (16 * 96)
#define NP_STRIPS (NP_W / 4)          // 56
#define NP_CHUNKS 8
#define NP_CROWS (NP_H / NP_CHUNKS)   // 28

struct Raw { float4 v; float lf, rt; };

__global__ __launch_bounds__(256) void NormPool2d_kernel(
    const float* __restrict__ x, float* __restrict__ out) {
    const int W = NP_W, H = NP_H;
    int f = blockIdx.x * blockDim.x + threadIdx.x;
    int strip = f % NP_STRIPS;
    int t = f / NP_STRIPS;
    int chunk = t % NP_CHUNKS;
    int plane = t / NP_CHUNKS;
    int w = strip * 4;

    const float* __restrict__ xp = x + (size_t)plane * (H * W);
    float* __restrict__ op = out + (size_t)plane * (H * W) + w;

    const bool left_edge = (w == 0);
    const bool right_edge = (w == W - 4);

    auto LOAD = [&](int h) -> Raw {
        Raw r;
        const float* row = xp + (size_t)h * W;
        r.v = *reinterpret_cast<const float4*>(row + w);
        r.lf = left_edge ? r.v.y : row[w - 1];    // reflect: x[-1] -> x[1]
        r.rt = right_edge ? r.v.z : row[w + 4];   // reflect: x[W] -> x[W-2]
        return r;
    };

    auto SUMS = [&](const Raw& r, float4& rs, float4& rq) {
        rs.x = r.lf + r.v.x + r.v.y;
        rs.y = r.v.x + r.v.y + r.v.z;
        rs.z = r.v.y + r.v.z + r.v.w;
        rs.w = r.v.z + r.v.w + r.rt;
        float l2 = r.lf * r.lf, a2 = r.v.x * r.v.x, b2 = r.v.y * r.v.y;
        float c2 = r.v.z * r.v.z, d2 = r.v.w * r.v.w, r2 = r.rt * r.rt;
        rq.x = l2 + a2 + b2;
        rq.y = a2 + b2 + c2;
        rq.z = b2 + c2 + d2;
        rq.w = c2 + d2 + r2;
    };

    auto finish = [&](float s, float q) -> float {
        float mean = s * (1.f / 9.f);
        float var = (q - s * mean) * 0.125f;  // unbiased: (ss - s^2/9)/8
        return mean - sqrtf(fmaxf(var, 0.f));
    };

    auto EMIT = [&](int h, const float4& s0, const float4& s1, const float4& s2,
                    const float4& q0, const float4& q1, const float4& q2) {
        float4 o;
        o.x = finish(s0.x + s1.x + s2.x, q0.x + q1.x + q2.x);
        o.y = finish(s0.y + s1.y + s2.y, q0.y + q1.y + q2.y);
        o.z = finish(s0.z + s1.z + s2.z, q0.z + q1.z + q2.z);
        o.w = finish(s0.w + s1.w + s2.w, q0.w + q1.w + q2.w);
        *reinterpret_cast<float4*>(op + (size_t)h * W) = o;
    };

    int r0 = chunk * NP_CROWS;
    int r1 = r0 + NP_CROWS;

    // Prologue: ps = sums(row r0-1 reflected), cs = sums(row r0),
    // nxt = raw(row r0+1) already in flight.
    Raw rawA = LOAD(r0 == 0 ? 1 : r0 - 1);
    Raw rawB = LOAD(r0);
    Raw nxt  = LOAD(r0 + 1);
    float4 ps, pq, cs, cq;
    SUMS(rawA, ps, pq);
    SUMS(rawB, cs, cq);

    // Invariant entering iteration h: ps=sums(h-1), cs=sums(h), nxt=raw(h+1).
    #pragma unroll 3
    for (int h = r0; h < r1 - 1; ++h) {
        int h2 = h + 2;
        if (h2 > H - 1) h2 = H - 2;   // reflect, only last chunk's last iter
        Raw nn = LOAD(h2);            // issue loads a full iteration early
        float4 ns, nq;
        SUMS(nxt, ns, nq);
        EMIT(h, ps, cs, ns, pq, cq, nq);
        ps = cs; pq = cq;
        cs = ns; cq = nq;
        nxt = nn;
    }
    // Epilogue: emit row r1-1 (nxt holds raw(r1) or its reflection).
    float4 ns, nq;
    SUMS(nxt, ns, nq);
    EMIT(r1 - 1, ps, cs, ns, pq, cq, nq);
}

extern "C" void kernel_launch(void* const* d_in, const int* in_sizes, int n_in,
                              void* d_out, int out_size, void* d_ws, size_t ws_size,
                              hipStream_t stream) {
    const float* x = (const float*)d_in[0];
    float* out = (float*)d_out;
    (void)in_sizes; (void)n_in; (void)out_size; (void)d_ws; (void)ws_size;

    const int total_threads = NP_PLANES * NP_CHUNKS * NP_STRIPS;  // 688128
    const int block = 256;
    const int grid = total_threads / block;  // 2688
    NormPool2d_kernel<<<grid, block, 0, stream>>>(x, out);
}